// Round 8
// baseline (201.965 us; speedup 1.0000x reference)
//
#include <hip/hip_runtime.h>
#include <math.h>

#define BSZ    4
#define NTOK   6400      // 40*160
#define DMODEL 256
#define NHEAD  8
#define HDIM   32
#define NPTS   9
#define HSP    40
#define WSP    160
#define KDIM   256
#define MTOT   (BSZ*NTOK)   // 25600

typedef short  short8  __attribute__((ext_vector_type(8)));
typedef float  floatx4 __attribute__((ext_vector_type(4)));
typedef float  f32x2   __attribute__((ext_vector_type(2)));

__device__ __forceinline__ ushort f2bf(float f) {
    uint u = __float_as_uint(f);
    u = (u + 0x7FFFu + ((u >> 16) & 1u)) >> 16;   // RNE
    return (ushort)u;
}

// unpack 8 packed bf16 (uint4) -> 4 x f32x2 (pairs, channel order preserved)
__device__ __forceinline__ void unpack8v(uint4 u, f32x2* f) {
    f[0].x = __uint_as_float(u.x << 16); f[0].y = __uint_as_float(u.x & 0xFFFF0000u);
    f[1].x = __uint_as_float(u.y << 16); f[1].y = __uint_as_float(u.y & 0xFFFF0000u);
    f[2].x = __uint_as_float(u.z << 16); f[2].y = __uint_as_float(u.z & 0xFFFF0000u);
    f[3].x = __uint_as_float(u.w << 16); f[3].y = __uint_as_float(u.w & 0xFFFF0000u);
}

// dot of 8 bf16 (packed in uint4) with q2[4] (f32x2 pairs) -> scalar
__device__ __forceinline__ float dot8(uint4 u, const f32x2* q2) {
    f32x2 a; a.x = 0.f; a.y = 0.f;
    f32x2 t;
    t.x = __uint_as_float(u.x << 16); t.y = __uint_as_float(u.x & 0xFFFF0000u);
    a += t * q2[0];
    t.x = __uint_as_float(u.y << 16); t.y = __uint_as_float(u.y & 0xFFFF0000u);
    a += t * q2[1];
    t.x = __uint_as_float(u.z << 16); t.y = __uint_as_float(u.z & 0xFFFF0000u);
    a += t * q2[2];
    t.x = __uint_as_float(u.w << 16); t.y = __uint_as_float(u.w & 0xFFFF0000u);
    a += t * q2[3];
    return a.x + a.y;
}

#define AS1C(p) ((const __attribute__((address_space(1))) void*)(p))
#define AS3(p)  ((__attribute__((address_space(3))) void*)(p))

// ---------------------------------------------------------------------------
// Weight-only fp32->bf16 casts (x is now consumed fp32 directly by gemm64<0>).
// 80 blocks x 4096 elems, 4 independent float4 chains per thread.
// Regions (4096-elem blocks o): wq[0,16) woff[16,25) pad[25,32) wkv[32,64)
//   wout[64,80)
// wf layout (1024x256 bf16): rows[0,256)=Wq [256,400)=Woff [400,512)=0
//   [512,1024)=Wkv
// ---------------------------------------------------------------------------
__global__ __launch_bounds__(256) void cast_all(
    const float* __restrict__ Wq, const float* __restrict__ Woff,
    const float* __restrict__ Wkv, const float* __restrict__ Wout,
    ushort* __restrict__ wf, ushort* __restrict__ woutb)
{
    const int o = blockIdx.x;
    if (o >= 25 && o < 32) {   // zero-fill wf rows 400..511 (28,672 elems)
        const int i = (o - 25) * 4096 + threadIdx.x * 4;
        ushort4 z; z.x = 0; z.y = 0; z.z = 0; z.w = 0;
        #pragma unroll
        for (int k = 0; k < 4; ++k)
            *(ushort4*)(wf + 400 * 256 + i + k * 1024) = z;
        return;
    }
    const float* src; ushort* dst; int base;
    if      (o < 16) { src = Wq;   dst = wf;              base = o; }
    else if (o < 25) { src = Woff; dst = wf + 256 * 256;  base = o - 16; }
    else if (o < 64) { src = Wkv;  dst = wf + 512 * 256;  base = o - 32; }
    else             { src = Wout; dst = woutb;           base = o - 64; }
    const int i0 = base * 4096 + threadIdx.x * 4;
    float4 v[4];
    #pragma unroll
    for (int k = 0; k < 4; ++k) v[k] = *(const float4*)(src + i0 + k * 1024);
    #pragma unroll
    for (int k = 0; k < 4; ++k) {
        ushort4 o4;
        o4.x = f2bf(v[k].x); o4.y = f2bf(v[k].y);
        o4.z = f2bf(v[k].z); o4.w = f2bf(v[k].w);
        *(ushort4*)(dst + i0 + k * 1024) = o4;
    }
}

// ---------------------------------------------------------------------------
// 64x64-tile 2-phase double-buffered GEMM (r6-proven TLP-first: 32 KB LDS ->
// 5 blocks/CU).  stage(t+1) BEFORE compute(t), ONE __syncthreads per K-step.
//
// MODE 0 A-path: reads x FP32 directly (kills the cast-x pass + xb HBM
//   round-trip, ~25 MB).  Reg-staged (T14 issue-early/write-late): float4 x4
//   loaded right after the barrier, converted+ds_written AFTER compute(t) so
//   HBM latency hides under MFMA.  ds_write applies the XOR slot swizzle
//   directly (slot ^ (row&7), 16B slots).
// MODE 1 A-path + both B-paths: global_load_lds bf16 with pre-swizzled
//   source (r3/r4-proven; FETCH 9 MB, conflicts 0).
// XCD map: token-panel p on XCD p/50 (cross-kernel affinity, r7-proven).
//
// MODE 0: N=1024 fused epilogue q/off/kv (grid 6400)
// MODE 1: N=256 fp32 out-projection     (grid 1600)
// ---------------------------------------------------------------------------
template <int MODE>
__global__ __launch_bounds__(256) void gemm64(
    const float*  __restrict__ Xf,     // MODE 0 A source (fp32)
    const ushort* __restrict__ Xb,     // MODE 1 A source (bf16)
    const ushort* __restrict__ Wf,
    const float* __restrict__ bq, const float* __restrict__ boff,
    const float* __restrict__ bkv,
    ushort* __restrict__ qb, float* __restrict__ off,
    ushort* __restrict__ kfb, ushort* __restrict__ vfb,
    float* __restrict__ Yout)
{
    constexpr int NBN = (MODE == 0) ? 16 : 4;  // 64-col n-blocks per m-panel
    __shared__ ushort As[2][64 * 64];          // 2 x 8 KB
    __shared__ ushort Bs[2][64 * 64];          // 2 x 8 KB

    const int tid = threadIdx.x;
    const int bid = blockIdx.x;
    const int xcd = bid & 7;
    const int j   = bid >> 3;
    const int block_n = (j % NBN) * 64;
    const int block_m = (xcd * 50 + j / NBN) * 64;   // 400 m-panels, 50/XCD

    const int wave = tid >> 6, lane = tid & 63;
    const int wr = (wave >> 1) * 32, wc = (wave & 1) * 32;
    const int l15 = lane & 15, quad = lane >> 4;

    const int srow  = lane >> 3;                 // 0..7
    const int sslot = (lane & 7) ^ srow;         // pre-swizzled src slot

    // MODE 0 A reg-staging map: thread t -> row t/4, col base (t&3)*16
    const int arow = tid >> 2;
    const int ac16 = (tid & 3) * 16;
    float4 areg[4];

    floatx4 acc[2][2];
    #pragma unroll
    for (int i = 0; i < 2; ++i)
        #pragma unroll
        for (int jj = 0; jj < 2; ++jj) {
            acc[i][jj][0] = 0.f; acc[i][jj][1] = 0.f;
            acc[i][jj][2] = 0.f; acc[i][jj][3] = 0.f;
        }

    auto loadA = [&](int kt) {           // MODE 0: issue fp32 A loads early
        if (MODE == 0) {
            const float* s = Xf + (size_t)(block_m + arow) * KDIM + kt + ac16;
            areg[0] = *(const float4*)(s + 0);
            areg[1] = *(const float4*)(s + 4);
            areg[2] = *(const float4*)(s + 8);
            areg[3] = *(const float4*)(s + 12);
        }
    };
    auto writeA = [&](int buf) {         // MODE 0: cvt + swizzled ds_write late
        if (MODE == 0) {
            uint pk[8];
            #pragma unroll
            for (int i = 0; i < 4; ++i) {
                pk[2 * i]     = (uint)f2bf(areg[i].x) | ((uint)f2bf(areg[i].y) << 16);
                pk[2 * i + 1] = (uint)f2bf(areg[i].z) | ((uint)f2bf(areg[i].w) << 16);
            }
            const int r7 = arow & 7;
            const int s0 = ac16 >> 3;          // logical 16B slot (even)
            uint4 w0; w0.x = pk[0]; w0.y = pk[1]; w0.z = pk[2]; w0.w = pk[3];
            uint4 w1; w1.x = pk[4]; w1.y = pk[5]; w1.z = pk[6]; w1.w = pk[7];
            *(uint4*)&As[buf][arow * 64 + ((s0 ^ r7) * 8)]       = w0;
            *(uint4*)&As[buf][arow * 64 + (((s0 + 1) ^ r7) * 8)] = w1;
        }
    };
    auto stageB = [&](int buf, int kt) {
        #pragma unroll
        for (int i = 0; i < 2; ++i) {
            const int rb = wave * 16 + i * 8;
            const ushort* sb = Wf + (size_t)(block_n + rb + srow) * KDIM + kt + sslot * 8;
            __builtin_amdgcn_global_load_lds(AS1C(sb), AS3(&Bs[buf][rb * 64]), 16, 0, 0);
            if (MODE == 1) {
                const ushort* sa = Xb + (size_t)(block_m + rb + srow) * KDIM + kt + sslot * 8;
                __builtin_amdgcn_global_load_lds(AS1C(sa), AS3(&As[buf][rb * 64]), 16, 0, 0);
            }
        }
    };

    auto compute = [&](int buf) {
        #pragma unroll
        for (int ks2 = 0; ks2 < 2; ++ks2) {
            short8 af[2], bfr[2];
            #pragma unroll
            for (int f = 0; f < 2; ++f) {
                const int ra  = wr + f * 16 + l15;
                const int rbb = wc + f * 16 + l15;
                const int sl  = (((ks2 * 4 + quad) ^ (l15 & 7))) * 8;
                af[f]  = *(const short8*)&As[buf][ra * 64 + sl];
                bfr[f] = *(const short8*)&Bs[buf][rbb * 64 + sl];
            }
            #pragma unroll
            for (int fm = 0; fm < 2; ++fm)
                #pragma unroll
                for (int fn = 0; fn < 2; ++fn)
                    acc[fm][fn] = __builtin_amdgcn_mfma_f32_16x16x32_bf16(
                        af[fm], bfr[fn], acc[fm][fn], 0, 0, 0);
        }
    };

    // prologue: tile 0 into buf 0
    loadA(0);
    stageB(0, 0);
    writeA(0);
    __syncthreads();
    // main: stage(t+1) issued before compute(t); A written after compute
    #pragma unroll
    for (int t = 0; t < 3; ++t) {
        loadA((t + 1) * 64);
        stageB((t + 1) & 1, (t + 1) * 64);
        compute(t & 1);
        writeA((t + 1) & 1);
        __syncthreads();
    }
    compute(1);   // tile 3 in buf 1

    // ---- epilogue: C/D layout col=lane&15, row=quad*4+reg ----
    const int bb  = block_m / NTOK;
    const int nn0 = block_m - bb * NTOK;
    #pragma unroll
    for (int fn = 0; fn < 2; ++fn) {
        const int col = block_n + wc + fn * 16 + l15;
        float bcol;
        if (MODE == 1) {
            bcol = bq[col];
        } else {
            if      (col < 256) bcol = bq[col];
            else if (col < 400) bcol = boff[col - 256];
            else if (col < 512) bcol = 0.f;
            else                bcol = bkv[col - 512];
        }
        #pragma unroll
        for (int fm = 0; fm < 2; ++fm) {
            #pragma unroll
            for (int r = 0; r < 4; ++r) {
                const int rloc = wr + fm * 16 + quad * 4 + r;
                const int row  = block_m + rloc;
                const float val = acc[fm][fn][r] + bcol;
                if (MODE == 1) {
                    Yout[(size_t)row * DMODEL + col] = val;
                } else {
                    if (col < 256) {
                        qb[(size_t)row * DMODEL + col] = f2bf(val);
                    } else if (col < 400) {
                        off[(size_t)row * 144 + (col - 256)] = tanhf(val) * 4.0f;
                    } else if (col >= 512) {
                        const int c2 = col - 512;
                        const int hh = (c2 & 255) >> 5, cc = c2 & 31;
                        const int nn = nn0 + rloc;
                        const size_t o = (((size_t)(bb * NHEAD + hh)) * NTOK + nn) * HDIM + cc;
                        if (c2 < 256) kfb[o] = f2bf(val);
                        else          vfb[o] = f2bf(val);
                    }
                }
            }
        }
    }
}

// ---------------------------------------------------------------------------
// Deformable sampling + softmax attention — FLAT dataflow.
// Plain-exp softmax (r7-proven: logits data-bounded, |l| << 1) makes the 9
// points fully independent: setup all idx/wt up front, flat K-phase (9 dots),
// exps, flat V-phase.  No group fences -> compiler schedules loads as deep as
// VGPR budget allows (r7 showed VGPR=64, bursts were serialized; no
// launch_bounds cap here).  q pre-scaled by 32^-0.5.
// XCD-affinity remap (r7-proven: FETCH 57->28 MB).
// ---------------------------------------------------------------------------
__global__ __launch_bounds__(256) void deform_attn(
    const ushort* __restrict__ qb,    // (M,256) bf16
    const float* __restrict__ off,    // (M,144) fp32 (tanh*4 applied)
    const ushort* __restrict__ kfb,   // (B*H,N,32) bf16
    const ushort* __restrict__ vfb,
    ushort* __restrict__ attnb)       // (M,256) bf16
{
    const int lane = threadIdx.x & 63;
    // affinity remap: o = (bid>>3) + (bid&7)*400  (bijective on [0,3200))
    const int o = ((int)blockIdx.x >> 3) + ((int)blockIdx.x & 7) * 400;
    const int token = o * 8 + (threadIdx.x >> 6) * 2 + (lane >> 5);
    const int h = (lane >> 2) & 7, lc = lane & 3;
    const int b = token / NTOK, n = token % NTOK;

    const uint4 qu = *(const uint4*)(qb + (size_t)token * DMODEL + h * HDIM + lc * 8);
    f32x2 q2[4]; unpack8v(qu, q2);
    #pragma unroll
    for (int i = 0; i < 4; ++i) q2[i] *= 0.17677669529663687f;   // 32^-0.5

    const float* ob = off + (size_t)token * 144 + h * (NPTS * 2);
    const float bx = (float)(n % WSP), by = (float)(n / WSP);
    const ushort* kbase = kfb + (size_t)(b * NHEAD + h) * NTOK * HDIM + lc * 8;
    const ushort* vbase = vfb + (size_t)(b * NHEAD + h) * NTOK * HDIM + lc * 8;

    // ---- setup: all 9 points ----
    int   idx[NPTS][4];
    float wt[NPTS][4];
    #pragma unroll
    for (int p = 0; p < NPTS; ++p) {
        const float2 of = *(const float2*)(ob + 2 * p);
        const float sx = bx + of.x, sy = by + of.y;
        const float fx0 = floorf(sx), fy0 = floorf(sy);
        const float wx1 = sx - fx0, wx0 = 1.0f - wx1;
        const float wy1 = sy - fy0, wy0 = 1.0f - wy1;
        const int ix0 = (int)fx0, iy0 = (int)fy0;
        const int ix1 = ix0 + 1, iy1 = iy0 + 1;
        const bool vx0 = (ix0 >= 0) & (ix0 <= WSP - 1);
        const bool vx1 = (ix1 >= 0) & (ix1 <= WSP - 1);
        const bool vy0 = (iy0 >= 0) & (iy0 <= HSP - 1);
        const bool vy1 = (iy1 >= 0) & (iy1 <= HSP - 1);
        const int cx0 = min(max(ix0, 0), WSP - 1);
        const int cx1 = min(max(ix1, 0), WSP - 1);
        const int cy0 = min(max(iy0, 0), HSP - 1);
        const int cy1 = min(max(iy1, 0), HSP - 1);
        wt[p][0] = wx0 * wy0 * (float)(vx0 && vy0);
        wt[p][1] = wx1 * wy0 * (float)(vx1 && vy0);
        wt[p][2] = wx0 * wy1 * (float)(vx0 && vy1);
        wt[p][3] = wx1 * wy1 * (float)(vx1 && vy1);
        idx[p][0] = (cy0 * WSP + cx0) * HDIM;
        idx[p][1] = (cy0 * WSP + cx1) * HDIM;
        idx[p][2] = (cy1 * WSP + cx0) * HDIM;
        idx[p][3] = (cy1 * WSP + cx1) * HDIM;
    }

    // ---- flat K phase: 9 independent dots ----
    float l[NPTS];
    #pragma unroll
    for (int p = 0; p < NPTS; ++p) {
        const uint4 k0 = *(const uint4*)(kbase + idx[p][0]);
        const uint4 k1 = *(const uint4*)(kbase + idx[p][1]);
        const uint4 k2 = *(const uint4*)(kbase + idx[p][2]);
        const uint4 k3 = *(const uint4*)(kbase + idx[p][3]);
        float part = wt[p][0] * dot8(k0, q2) + wt[p][1] * dot8(k1, q2)
                   + wt[p][2] * dot8(k2, q2) + wt[p][3] * dot8(k3, q2);
        part += __shfl_xor(part, 1, 64);
        part += __shfl_xor(part, 2, 64);
        l[p] = part;
    }

    // ---- softmax weights (no max-tracking; |l| bounded) ----
    float s = 0.f, e[NPTS];
    #pragma unroll
    for (int p = 0; p < NPTS; ++p) { e[p] = __expf(l[p]); s += e[p]; }

    // ---- flat V phase ----
    f32x2 o2[4];
    #pragma unroll
    for (int i = 0; i < 4; ++i) { o2[i].x = 0.f; o2[i].y = 0.f; }
    #pragma unroll
    for (int p = 0; p < NPTS; ++p) {
        #pragma unroll
        for (int c = 0; c < 4; ++c) {
            const uint4 vu = *(const uint4*)(vbase + idx[p][c]);
            f32x2 vv[4]; unpack8v(vu, vv);
            const float ew = e[p] * wt[p][c];
            #pragma unroll
            for (int i = 0; i < 4; ++i) o2[i] += vv[i] * ew;
        }
    }

    const float inv = 1.0f / s;
    uint4 ru;
    ru.x = (uint)f2bf(o2[0].x * inv) | ((uint)f2bf(o2[0].y * inv) << 16);
    ru.y = (uint)f2bf(o2[1].x * inv) | ((uint)f2bf(o2[1].y * inv) << 16);
    ru.z = (uint)f2bf(o2[2].x * inv) | ((uint)f2bf(o2[2].y * inv) << 16);
    ru.w = (uint)f2bf(o2[3].x * inv) | ((uint)f2bf(o2[3].y * inv) << 16);
    *(uint4*)(attnb + (size_t)token * DMODEL + h * HDIM + lc * 8) = ru;
}

// ---------------------------------------------------------------------------
extern "C" void kernel_launch(void* const* d_in, const int* in_sizes, int n_in,
                              void* d_out, int out_size, void* d_ws, size_t ws_size,
                              hipStream_t stream) {
    const float* x    = (const float*)d_in[0];
    const float* Wq   = (const float*)d_in[1];
    const float* bq   = (const float*)d_in[2];
    const float* Woff = (const float*)d_in[3];
    const float* boff = (const float*)d_in[4];
    const float* Wkv  = (const float*)d_in[5];
    const float* bkv  = (const float*)d_in[6];
    const float* Wout = (const float*)d_in[7];
    const float* bout = (const float*)d_in[8];

    // workspace layout (~68 MB)
    ushort* attnb = (ushort*)d_ws;                           // 6,553,600 us
    ushort* qb    = attnb + (size_t)MTOT * DMODEL;           // 6,553,600 us
    float*  off   = (float*)(qb + (size_t)MTOT * DMODEL);    // 3,686,400 f32
    ushort* kfb   = (ushort*)(off + (size_t)MTOT * 144);     // 6,553,600 us
    ushort* vfb   = kfb + (size_t)MTOT * DMODEL;             // 6,553,600 us
    ushort* wf    = vfb + (size_t)MTOT * DMODEL;             // 262,144 us (1024x256)
    ushort* woutb = wf + 262144;                             // 65,536 us

    cast_all<<<dim3(80), dim3(256), 0, stream>>>(Wq, Woff, Wkv, Wout, wf, woutb);

    gemm64<0><<<dim3(6400), dim3(256), 0, stream>>>(x, nullptr, wf, bq, boff, bkv,
                                                    qb, off, kfb, vfb, nullptr);

    deform_attn<<<dim3(3200), dim3(256), 0, stream>>>(qb, off, kfb, vfb, attnb);

    gemm64<1><<<dim3(1600), dim3(256), 0, stream>>>(nullptr, attnb, woutb, bout,
                                                    nullptr, nullptr, nullptr,
                                                    nullptr, nullptr, nullptr,
                                                    (float*)d_out);
}